// Round 11
// baseline (477.759 us; speedup 1.0000x reference)
//
#include <hip/hip_runtime.h>
#include <math.h>

// ---------------- problem constants ----------------
constexpr int   NN  = 100000;    // nodes
constexpr int   EE  = 1600000;   // edges
constexpr int   HH  = 128;       // hidden / in_channels
constexpr int   GG  = 128;       // graphs
constexpr float EPSV = 1e-5f;
constexpr int   NSB = 256;                     // global sub-bins
constexpr int   SUBW = (NN + NSB - 1) / NSB;   // 391 nodes per sub-bin
constexpr int   CAP2 = 8192;                   // per-sub-bin capacity (avg 6250, +24 sigma)
constexpr int   GEMM_BLOCKS = (NN + 127) / 128;  // 782

typedef __attribute__((ext_vector_type(8))) short  short8;
typedef __attribute__((ext_vector_type(4))) float  f32x4;
typedef __attribute__((ext_vector_type(2))) float  v2f;

__device__ __forceinline__ unsigned short f2bf(float f) {
    union { float f; unsigned u; } v; v.f = f;
    unsigned r = v.u + 0x7FFF + ((v.u >> 16) & 1);   // round-to-nearest-even
    return (unsigned short)(r >> 16);
}
__device__ __forceinline__ float bf2f(unsigned short b) {
    union { unsigned u; float f; } v; v.u = ((unsigned)b) << 16;
    return v.f;
}
__device__ __forceinline__ v2f unpk(unsigned u) {
    v2f r;
    r.x = __int_as_float((int)(u << 16));
    r.y = __int_as_float((int)(u & 0xffff0000u));
    return r;
}

// ---------------- workspace layout ----------------
constexpr size_t A256(size_t x) { return (x + 255) & ~(size_t)255; }
constexpr size_t OFF_TL  = 0;                                       // tail2[256]
constexpr size_t OFF_DNV = A256(OFF_TL  + 256 * 4);                 // N floats dinv
constexpr size_t OFF_RP  = A256(OFF_DNV + (size_t)NN * 4);          // (N+1) ints
constexpr size_t OFF_SRC = A256(OFF_RP  + (size_t)(NN + 1) * 4);    // E ints sorted src
constexpr size_t OFF_B2  = A256(OFF_SRC + (size_t)EE * 4);          // 256*CAP2 uints sub-bins
constexpr size_t OFF_ED  = A256(OFF_B2  + (size_t)NSB * CAP2 * 4);  // E uint2 (src, dinv[src])
constexpr size_t OFF_HW  = A256(OFF_ED  + (size_t)EE * 8);          // N*H bf16 (h@W)
constexpr size_t OFF_H0  = A256(OFF_HW  + (size_t)NN * HH * 2);     // N*H bf16 (h)
constexpr size_t OFF_PL  = A256(OFF_H0  + (size_t)NN * HH * 2);     // G*H f32 pooled + G f32 cnt

// ---------------- GEMM body: C[N,128] = A[N,128] @ W[128,128], MFMA bf16, split-W ----------------
template<bool FP32A>
__device__ __forceinline__ void gemm_body(const void* __restrict__ Ap,
                                          const float* __restrict__ W,
                                          unsigned short* __restrict__ C,
                                          int nrows, int rb) {
    __shared__ unsigned short WtH[64 * 136];  // reused as Cs[128][68] in epilogue
    __shared__ unsigned short WtL[64 * 136];
    int t = threadIdx.x;
    int row0 = rb * 128;
    int wv = t >> 6, lane = t & 63, m = lane & 15, q = lane >> 4;
    long rowA = row0 + wv * 32 + m;
    long rowB = rowA + 16;

    short8 a[2][4];
#pragma unroll
    for (int kc = 0; kc < 4; ++kc) {
        int ko = kc * 32 + q * 8;
        if (FP32A) {
            const float* Af = (const float*)Ap;
            float4 f0 = {0,0,0,0}, f1 = {0,0,0,0}, g0 = {0,0,0,0}, g1 = {0,0,0,0};
            if (rowA < nrows) {
                f0 = *(const float4*)(Af + rowA * 128 + ko);
                f1 = *(const float4*)(Af + rowA * 128 + ko + 4);
            }
            if (rowB < nrows) {
                g0 = *(const float4*)(Af + rowB * 128 + ko);
                g1 = *(const float4*)(Af + rowB * 128 + ko + 4);
            }
            union { short8 s; unsigned short u[8]; } ua, ub;
            ua.u[0] = f2bf(f0.x); ua.u[1] = f2bf(f0.y); ua.u[2] = f2bf(f0.z); ua.u[3] = f2bf(f0.w);
            ua.u[4] = f2bf(f1.x); ua.u[5] = f2bf(f1.y); ua.u[6] = f2bf(f1.z); ua.u[7] = f2bf(f1.w);
            ub.u[0] = f2bf(g0.x); ub.u[1] = f2bf(g0.y); ub.u[2] = f2bf(g0.z); ub.u[3] = f2bf(g0.w);
            ub.u[4] = f2bf(g1.x); ub.u[5] = f2bf(g1.y); ub.u[6] = f2bf(g1.z); ub.u[7] = f2bf(g1.w);
            a[0][kc] = ua.s; a[1][kc] = ub.s;
        } else {
            const unsigned short* Ab = (const unsigned short*)Ap;
            short8 z = {};
            a[0][kc] = (rowA < nrows) ? *(const short8*)(Ab + rowA * 128 + ko) : z;
            a[1][kc] = (rowB < nrows) ? *(const short8*)(Ab + rowB * 128 + ko) : z;
        }
    }

    for (int half = 0; half < 2; ++half) {
        int c0 = half * 64;
        __syncthreads();
        for (int idx = t; idx < 64 * 128; idx += 256) {
            int k = idx >> 6, c = idx & 63;
            float w = W[k * 128 + c0 + c];
            unsigned short hb = f2bf(w);
            WtH[c * 136 + k] = hb;
            WtL[c * 136 + k] = f2bf(w - bf2f(hb));
        }
        __syncthreads();
        f32x4 acc[2][4] = {};
#pragma unroll
        for (int kc = 0; kc < 4; ++kc) {
            int ko = kc * 32 + q * 8;
#pragma unroll
            for (int ct = 0; ct < 4; ++ct) {
                short8 bh = *(const short8*)(WtH + (ct * 16 + m) * 136 + ko);
                short8 bl = *(const short8*)(WtL + (ct * 16 + m) * 136 + ko);
                acc[0][ct] = __builtin_amdgcn_mfma_f32_16x16x32_bf16(a[0][kc], bh, acc[0][ct], 0, 0, 0);
                acc[0][ct] = __builtin_amdgcn_mfma_f32_16x16x32_bf16(a[0][kc], bl, acc[0][ct], 0, 0, 0);
                acc[1][ct] = __builtin_amdgcn_mfma_f32_16x16x32_bf16(a[1][kc], bh, acc[1][ct], 0, 0, 0);
                acc[1][ct] = __builtin_amdgcn_mfma_f32_16x16x32_bf16(a[1][kc], bl, acc[1][ct], 0, 0, 0);
            }
        }
        __syncthreads();
        unsigned short* Cs = WtH;  // [128][68]
#pragma unroll
        for (int rt = 0; rt < 2; ++rt)
#pragma unroll
            for (int ct = 0; ct < 4; ++ct)
#pragma unroll
                for (int r = 0; r < 4; ++r) {
                    int rl = wv * 32 + rt * 16 + q * 4 + r;
                    Cs[rl * 68 + ct * 16 + m] = f2bf(acc[rt][ct][r]);
                }
        __syncthreads();
        for (int idx = t; idx < 128 * 16; idx += 256) {
            int row = idx >> 4, ch = idx & 15;
            long grow = row0 + row;
            if (grow < nrows)
                *(ushort4*)(C + grow * 128 + c0 + ch * 4) = *(const ushort4*)(Cs + row * 68 + ch * 4);
        }
    }
}

// ---------------- direct binning: edges -> 256 global sub-bins ----------------
__device__ void binall_body(const int* __restrict__ src, const int* __restrict__ dst,
                            unsigned* __restrict__ bins2, unsigned* __restrict__ tail2,
                            int b) {
    __shared__ unsigned cnt[NSB];
    __shared__ unsigned cur[NSB];
    int t = threadIdx.x;
    cnt[t] = 0;
    __syncthreads();
    const int nvec = EE / 4;                 // 400000
    int csz = (nvec + NSB - 1) / NSB;        // 1563
    int i0 = b * csz;
    int i1 = i0 + csz; if (i1 > nvec) i1 = nvec;
    const int4* d4 = (const int4*)dst;
    const int4* s4 = (const int4*)src;
    for (int i = i0 + t; i < i1; i += 256) {
        int4 d = d4[i];
        atomicAdd(&cnt[(unsigned)d.x / SUBW], 1u);
        atomicAdd(&cnt[(unsigned)d.y / SUBW], 1u);
        atomicAdd(&cnt[(unsigned)d.z / SUBW], 1u);
        atomicAdd(&cnt[(unsigned)d.w / SUBW], 1u);
    }
    __syncthreads();
    cur[t] = atomicAdd(&tail2[t], cnt[t]);   // base within sub-bin region
    __syncthreads();
    for (int i = i0 + t; i < i1; i += 256) {
        int4 d = d4[i];
        int4 s = s4[i];
        int dd[4] = {d.x, d.y, d.z, d.w};
        int ss[4] = {s.x, s.y, s.z, s.w};
#pragma unroll
        for (int c = 0; c < 4; ++c) {
            unsigned gsb = (unsigned)dd[c] / SUBW;
            unsigned p = atomicAdd(&cur[gsb], 1u);
            if (p < (unsigned)CAP2)
                bins2[(size_t)gsb * CAP2 + p] =
                    ((unsigned)(dd[c] - gsb * SUBW) << 17) | (unsigned)ss[c];
        }
    }
}

// ---------------- K1: gemm layer 0 (fp32 A) || binall, block-range split ----------------
__global__ __launch_bounds__(256) void k_gemm0_bin(const float* __restrict__ x,
                                                   const float* __restrict__ W,
                                                   unsigned short* __restrict__ C,
                                                   const int* __restrict__ src,
                                                   const int* __restrict__ dst,
                                                   unsigned* __restrict__ bins2,
                                                   unsigned* __restrict__ tail2) {
    if (blockIdx.x < GEMM_BLOCKS)
        gemm_body<true>(x, W, C, NN, blockIdx.x);
    else
        binall_body(src, dst, bins2, tail2, blockIdx.x - GEMM_BLOCKS);
}

__global__ __launch_bounds__(256) void k_gemm(const unsigned short* __restrict__ A,
                                              const float* __restrict__ W,
                                              unsigned short* __restrict__ C) {
    gemm_body<false>(A, W, C, NN, blockIdx.x);
}

// ---------------- k_build: tail-prefix + hist + scan -> rp,dinv + scatter, fused ----------------
__global__ __launch_bounds__(256) void k_build(const unsigned* __restrict__ bins2,
                                               const unsigned* __restrict__ tail2,
                                               int* __restrict__ rp,
                                               float* __restrict__ dinv,
                                               int* __restrict__ ssrc,
                                               float* __restrict__ pooled) {
    __shared__ int hist[SUBW];           // hist -> cursors
    __shared__ int sa[512], sd[512];
    __shared__ unsigned ta[256], tb[256];
    int b = blockIdx.x, t = threadIdx.x;

    if (b < 65) {
        int idx = b * 256 + t;
        if (idx < GG * HH + GG) pooled[idx] = 0.f;
    }

    unsigned v = tail2[t];
    ta[t] = v;
    __syncthreads();
    unsigned *sp = ta, *dp = tb;
    for (int off = 1; off < 256; off <<= 1) {
        dp[t] = sp[t] + ((t >= off) ? sp[t - off] : 0u);
        __syncthreads();
        unsigned* tmp = sp; sp = dp; dp = tmp;
    }
    unsigned base = sp[b] - tail2[b];    // exclusive prefix for this sub-bin
    unsigned m = tail2[b];
    if (m > (unsigned)CAP2) m = CAP2;

    int lo = b * SUBW;
    int nn = NN - lo; if (nn > SUBW) nn = SUBW;
    for (int i = t; i < nn; i += 256) hist[i] = 0;
    __syncthreads();

    const unsigned* bb = bins2 + (size_t)b * CAP2;
    unsigned nv = m >> 2;
    for (unsigned i = t; i < nv; i += 256) {
        uint4 u = ((const uint4*)bb)[i];
        atomicAdd(&hist[u.x >> 17], 1);
        atomicAdd(&hist[u.y >> 17], 1);
        atomicAdd(&hist[u.z >> 17], 1);
        atomicAdd(&hist[u.w >> 17], 1);
    }
    for (unsigned i = (m & ~3u) + t; i < m; i += 256)
        atomicAdd(&hist[bb[i] >> 17], 1);
    __syncthreads();

    sa[t]       = (t < nn)       ? hist[t]       : 0;
    sa[t + 256] = (t + 256 < nn) ? hist[t + 256] : 0;
    __syncthreads();
    int* s = sa; int* d = sd;
    for (int off = 1; off < 512; off <<= 1) {
        d[t]       = s[t]       + ((t >= off)       ? s[t - off]       : 0);
        d[t + 256] = s[t + 256] + ((t + 256 >= off) ? s[t + 256 - off] : 0);
        __syncthreads();
        int* tmp = s; s = d; d = tmp;
    }

    for (int i = t; i < nn; i += 256) {
        int cur0 = (int)base + (i ? s[i - 1] : 0);
        rp[lo + i]   = cur0;
        dinv[lo + i] = rsqrtf((float)(hist[i] + 1));  // +1 self-loop
    }
    __syncthreads();
    for (int i = t; i < nn; i += 256)
        hist[i] = (int)base + (i ? s[i - 1] : 0);
    if (b == 255 && t == 0) rp[NN] = EE;
    __syncthreads();

    for (unsigned i = t; i < nv; i += 256) {
        uint4 u = ((const uint4*)bb)[i];
        int p;
        p = atomicAdd(&hist[u.x >> 17], 1); ssrc[p] = (int)(u.x & 0x1FFFFu);
        p = atomicAdd(&hist[u.y >> 17], 1); ssrc[p] = (int)(u.y & 0x1FFFFu);
        p = atomicAdd(&hist[u.z >> 17], 1); ssrc[p] = (int)(u.z & 0x1FFFFu);
        p = atomicAdd(&hist[u.w >> 17], 1); ssrc[p] = (int)(u.w & 0x1FFFFu);
    }
    for (unsigned i = (m & ~3u) + t; i < m; i += 256) {
        unsigned u = bb[i];
        int p = atomicAdd(&hist[u >> 17], 1);
        ssrc[p] = (int)(u & 0x1FFFFu);
    }
}

// ---------------- edata: (src, dinv[src]) per edge -- pays the random dinv
// gather ONCE instead of once per k_agg layer (R10 lesson: that gather plus
// 2 readlanes/edge made k_agg issue-bound at VALUBusy 57%).
__global__ void k_edata(const int* __restrict__ ssrc, const float* __restrict__ dinv,
                        uint2* __restrict__ edata) {
    int i = blockIdx.x * 256 + threadIdx.x;
    if (i < EE) {
        int s = ssrc[i];
        edata[i] = make_uint2((unsigned)s, __float_as_uint(dinv[s]));
    }
}

// ---------------- aggregate + bias + BN + ReLU ----------------
// 4 edges per wave (16 lanes x 8ch dwordx4 each); metadata via shfl(bpermute);
// group-reduce with shfl_xor(16,32); one uint4 store per 16 lanes.
__global__ __launch_bounds__(256) void k_agg(const unsigned short* __restrict__ hw,
                                             const int* __restrict__ rp,
                                             const uint2* __restrict__ edata,
                                             const float* __restrict__ dinv,
                                             const float* __restrict__ bsl,
                                             const float* __restrict__ gamma,
                                             const float* __restrict__ beta,
                                             const float* __restrict__ rm,
                                             const float* __restrict__ rv,
                                             unsigned short* __restrict__ out) {
    int lane = threadIdx.x & 63;
    int grp  = lane >> 4;                 // edge group 0..3
    int c8   = (lane & 15) * 8;           // channel base (8 ch/lane)
    int n = blockIdx.x * 4 + (threadIdx.x >> 6);
    int beg = rp[n], end = rp[n + 1];

    v2f a0 = {0.f,0.f}, a1 = {0.f,0.f}, a2 = {0.f,0.f}, a3 = {0.f,0.f};

    for (int chunk = beg; chunk < end; chunk += 64) {
        int l = chunk + lane;
        uint2 ed = (l < end) ? edata[l] : make_uint2((unsigned)n, 0u);  // pad: self row, w=0
        int cnt = end - chunk;
        if (cnt > 64) cnt = 64;
#pragma unroll 4
        for (int jb = 0; jb < cnt; jb += 4) {
            int srcl = jb + grp;                               // <=63 always
            int s    = __shfl((int)ed.x, srcl);
            float dv = __int_as_float(__shfl((int)ed.y, srcl));
            uint4 u  = *(const uint4*)(hw + (size_t)s * HH + c8);
            v2f d2 = {dv, dv};
            a0 += d2 * unpk(u.x);
            a1 += d2 * unpk(u.y);
            a2 += d2 * unpk(u.z);
            a3 += d2 * unpk(u.w);
        }
    }
    // reduce the 4 edge groups (lanes with same lane&15 share channels)
#define REDUCE(f) f += __shfl_xor(f, 16); f += __shfl_xor(f, 32)
    REDUCE(a0.x); REDUCE(a0.y); REDUCE(a1.x); REDUCE(a1.y);
    REDUCE(a2.x); REDUCE(a2.y); REDUCE(a3.x); REDUCE(a3.y);
#undef REDUCE

    // self-loop + scale (computed redundantly by all groups; stored by grp 0)
    float di = dinv[n];
    {
        uint4 u = *(const uint4*)(hw + (size_t)n * HH + c8);
        v2f d2 = {di, di};
        a0 += d2 * unpk(u.x);
        a1 += d2 * unpk(u.y);
        a2 += d2 * unpk(u.z);
        a3 += d2 * unpk(u.w);
    }
    v2f dd = {di, di};
    a0 *= dd; a1 *= dd; a2 *= dd; a3 *= dd;

    if (grp == 0) {
        float4 g0 = *(const float4*)(gamma + c8), g1 = *(const float4*)(gamma + c8 + 4);
        float4 r0 = *(const float4*)(rv + c8),    r1 = *(const float4*)(rv + c8 + 4);
        float4 m0 = *(const float4*)(rm + c8),    m1 = *(const float4*)(rm + c8 + 4);
        float4 t0 = *(const float4*)(beta + c8),  t1 = *(const float4*)(beta + c8 + 4);
        float4 b0 = *(const float4*)(bsl + c8),   b1 = *(const float4*)(bsl + c8 + 4);
        float sc[8] = { g0.x * rsqrtf(r0.x + EPSV), g0.y * rsqrtf(r0.y + EPSV),
                        g0.z * rsqrtf(r0.z + EPSV), g0.w * rsqrtf(r0.w + EPSV),
                        g1.x * rsqrtf(r1.x + EPSV), g1.y * rsqrtf(r1.y + EPSV),
                        g1.z * rsqrtf(r1.z + EPSV), g1.w * rsqrtf(r1.w + EPSV) };
        float bb[8] = { fmaf(b0.x - m0.x, sc[0], t0.x), fmaf(b0.y - m0.y, sc[1], t0.y),
                        fmaf(b0.z - m0.z, sc[2], t0.z), fmaf(b0.w - m0.w, sc[3], t0.w),
                        fmaf(b1.x - m1.x, sc[4], t1.x), fmaf(b1.y - m1.y, sc[5], t1.y),
                        fmaf(b1.z - m1.z, sc[6], t1.z), fmaf(b1.w - m1.w, sc[7], t1.w) };
        float y[8] = { fmaxf(fmaf(a0.x, sc[0], bb[0]), 0.f), fmaxf(fmaf(a0.y, sc[1], bb[1]), 0.f),
                       fmaxf(fmaf(a1.x, sc[2], bb[2]), 0.f), fmaxf(fmaf(a1.y, sc[3], bb[3]), 0.f),
                       fmaxf(fmaf(a2.x, sc[4], bb[4]), 0.f), fmaxf(fmaf(a2.y, sc[5], bb[5]), 0.f),
                       fmaxf(fmaf(a3.x, sc[6], bb[6]), 0.f), fmaxf(fmaf(a3.y, sc[7], bb[7]), 0.f) };
        uint4 o;
        o.x = (unsigned)f2bf(y[0]) | ((unsigned)f2bf(y[1]) << 16);
        o.y = (unsigned)f2bf(y[2]) | ((unsigned)f2bf(y[3]) << 16);
        o.z = (unsigned)f2bf(y[4]) | ((unsigned)f2bf(y[5]) << 16);
        o.w = (unsigned)f2bf(y[6]) | ((unsigned)f2bf(y[7]) << 16);
        *(uint4*)(out + (size_t)n * HH + c8) = o;
    }
}

// ---------------- global mean pool (batch sorted, bf16 input) ----------------
__global__ __launch_bounds__(128) void k_pool(const unsigned short* __restrict__ h,
                                              const int* __restrict__ batch,
                                              float* __restrict__ pooled,
                                              float* __restrict__ cnt) {
    int t = threadIdx.x;
    const int chunk = (NN + 1023) / 1024;
    int n0 = blockIdx.x * chunk;
    if (n0 >= NN) return;
    int n1 = n0 + chunk;
    if (n1 > NN) n1 = NN;
    int cur = batch[n0];
    float acc = 0.f;
    int k = 0;
    for (int n = n0; n < n1; ++n) {
        int b = batch[n];
        if (b != cur) {
            atomicAdd(&pooled[(size_t)cur * 128 + t], acc);
            if (t == 0) atomicAdd(&cnt[cur], (float)k);
            acc = 0.f; k = 0; cur = b;
        }
        acc += bf2f(h[(size_t)n * 128 + t]);
        ++k;
    }
    atomicAdd(&pooled[(size_t)cur * 128 + t], acc);
    if (t == 0) atomicAdd(&cnt[cur], (float)k);
}

// ---------------- LSTM (single step, h0=c0=0) + FC ----------------
__global__ __launch_bounds__(128) void k_head(const float* __restrict__ pooled,
                                              const float* __restrict__ cnt,
                                              const float* __restrict__ W_ih,
                                              const float* __restrict__ b_ih,
                                              const float* __restrict__ b_hh,
                                              const float* __restrict__ W_fc,
                                              const float* __restrict__ b_fc,
                                              float* __restrict__ out) {
    __shared__ float pm[128];
    __shared__ float gate[512];
    __shared__ float hn[128];
    int g = blockIdx.x, t = threadIdx.x;
    float cdiv = fmaxf(cnt[g], 1.0f);
    pm[t] = pooled[(size_t)g * 128 + t] / cdiv;
    __syncthreads();
    for (int j = t; j < 512; j += 128) {
        float acc = b_ih[j] + b_hh[j];
        const float* w = W_ih + (size_t)j * 128;
#pragma unroll 8
        for (int k = 0; k < 128; ++k) acc = fmaf(pm[k], w[k], acc);
        gate[j] = acc;
    }
    __syncthreads();
    {
        float gi = gate[t], gg = gate[256 + t], go = gate[384 + t];
        float cc = (1.f / (1.f + expf(-gi))) * tanhf(gg);
        hn[t] = (1.f / (1.f + expf(-go))) * tanhf(cc);
    }
    __syncthreads();
    if (t < 16) {
        float acc = b_fc[t];
        const float* w = W_fc + (size_t)t * 128;
#pragma unroll 8
        for (int k = 0; k < 128; ++k) acc = fmaf(hn[k], w[k], acc);
        out[(size_t)g * 16 + t] = acc;
    }
}

// ---------------- launch ----------------
extern "C" void kernel_launch(void* const* d_in, const int* in_sizes, int n_in,
                              void* d_out, int out_size, void* d_ws, size_t ws_size,
                              hipStream_t stream) {
    const float* x      = (const float*)d_in[0];
    const int*   ei     = (const int*)d_in[1];
    const int*   src    = ei;
    const int*   dst    = ei + EE;
    const int*   batch  = (const int*)d_in[2];
    const float* Ws     = (const float*)d_in[3];
    const float* bs     = (const float*)d_in[4];
    const float* gammas = (const float*)d_in[5];
    const float* betas  = (const float*)d_in[6];
    const float* rms    = (const float*)d_in[7];
    const float* rvs    = (const float*)d_in[8];
    const float* W_ih   = (const float*)d_in[9];
    // d_in[10] = W_hh (unused: h0 = 0)
    const float* b_ih   = (const float*)d_in[11];
    const float* b_hh   = (const float*)d_in[12];
    const float* W_fc   = (const float*)d_in[13];
    const float* b_fc   = (const float*)d_in[14];
    float* out = (float*)d_out;

    char* w = (char*)d_ws;
    unsigned*       tail2  = (unsigned*)(w + OFF_TL);
    float*          dinv   = (float*)(w + OFF_DNV);
    int*            rp     = (int*)(w + OFF_RP);
    int*            ssrc   = (int*)(w + OFF_SRC);
    unsigned*       bins2  = (unsigned*)(w + OFF_B2);
    uint2*          edata  = (uint2*)(w + OFF_ED);
    unsigned short* hwb    = (unsigned short*)(w + OFF_HW);
    unsigned short* h0     = (unsigned short*)(w + OFF_H0);
    float*          pooled = (float*)(w + OFF_PL);
    float*          cntb   = pooled + (size_t)GG * HH;

    hipMemsetAsync(tail2, 0, 256 * 4, stream);

    k_gemm0_bin<<<GEMM_BLOCKS + NSB, 256, 0, stream>>>(x, Ws, hwb, src, dst, bins2, tail2);
    k_build<<<NSB, 256, 0, stream>>>(bins2, tail2, rp, dinv, ssrc, pooled);
    k_edata<<<(EE + 255) / 256, 256, 0, stream>>>(ssrc, dinv, edata);

    for (int l = 0; l < 3; ++l) {
        if (l > 0)
            k_gemm<<<GEMM_BLOCKS, 256, 0, stream>>>(h0, Ws + (size_t)l * 128 * 128, hwb);
        k_agg<<<(NN + 3) / 4, 256, 0, stream>>>(hwb, rp, edata, dinv,
                                                bs + l * 128, gammas + l * 128, betas + l * 128,
                                                rms + l * 128, rvs + l * 128, h0);
    }
    k_pool<<<1024, 128, 0, stream>>>(h0, batch, pooled, cntb);
    k_head<<<GG, 128, 0, stream>>>(pooled, cntb, W_ih, b_ih, b_hh, W_fc, b_fc, out);
}

// Round 12
// 435.862 us; speedup vs baseline: 1.0961x; 1.0961x over previous
//
#include <hip/hip_runtime.h>
#include <math.h>

// ---------------- problem constants ----------------
constexpr int   NN  = 100000;    // nodes
constexpr int   EE  = 1600000;   // edges
constexpr int   HH  = 128;       // hidden / in_channels
constexpr int   GG  = 128;       // graphs
constexpr float EPSV = 1e-5f;
constexpr int   NSB = 256;                     // global sub-bins
constexpr int   SUBW = (NN + NSB - 1) / NSB;   // 391 nodes per sub-bin
constexpr int   CAP2 = 8192;                   // per-sub-bin capacity (avg 6250, +24 sigma)
constexpr int   GEMM_BLOCKS = (NN + 127) / 128;  // 782
constexpr int   EDATA_BLOCKS = (EE + 255) / 256; // 6250
constexpr int   WHALF = 64 * 136;                // padded ushorts per (half,hl) slab = 8704
constexpr int   WLAYER = 2 * 2 * WHALF;          // per-layer split-W ushorts (2 halves x H/L)

typedef __attribute__((ext_vector_type(8))) short  short8;
typedef __attribute__((ext_vector_type(4))) float  f32x4;
typedef __attribute__((ext_vector_type(2))) float  v2f;

__device__ __forceinline__ unsigned short f2bf(float f) {
    union { float f; unsigned u; } v; v.f = f;
    unsigned r = v.u + 0x7FFF + ((v.u >> 16) & 1);   // round-to-nearest-even
    return (unsigned short)(r >> 16);
}
__device__ __forceinline__ float bf2f(unsigned short b) {
    union { unsigned u; float f; } v; v.u = ((unsigned)b) << 16;
    return v.f;
}

// ---------------- workspace layout ----------------
constexpr size_t A256(size_t x) { return (x + 255) & ~(size_t)255; }
constexpr size_t OFF_TL  = 0;                                       // tail2[256]
constexpr size_t OFF_DNV = A256(OFF_TL  + 256 * 4);                 // N floats dinv
constexpr size_t OFF_RP  = A256(OFF_DNV + (size_t)NN * 4);          // (N+1) ints
constexpr size_t OFF_SRC = A256(OFF_RP  + (size_t)(NN + 1) * 4);    // E ints sorted src
constexpr size_t OFF_B2  = A256(OFF_SRC + (size_t)EE * 4);          // 256*CAP2 uints sub-bins
constexpr size_t OFF_ED  = A256(OFF_B2  + (size_t)NSB * CAP2 * 4);  // E uint2 (src, dinv[src])
constexpr size_t OFF_WS  = A256(OFF_ED  + (size_t)EE * 8);          // 2*WLAYER ushorts split-W (layers 1,2)
constexpr size_t OFF_HW  = A256(OFF_WS  + (size_t)2 * WLAYER * 2);  // N*H bf16 (h@W)
constexpr size_t OFF_H0  = A256(OFF_HW  + (size_t)NN * HH * 2);     // N*H bf16 (h)
constexpr size_t OFF_PL  = A256(OFF_H0  + (size_t)NN * HH * 2);     // G*H f32 pooled + G f32 cnt

// ---------------- GEMM body: C[N,128] = A[N,128] @ W[128,128], MFMA bf16, split-W ----------------
// R12: bf16 layers load PRE-SPLIT W (global, exact LDS layout) -> staging is a
// straight uint4 memcpy. (R11 lesson: per-block fp32->split conversion cost
// ~1536 VALU-cyc/wave, MORE than the 1024 MFMA cycles.) fp32 layer-0 keeps
// inline split (runs before the prep kernel).
template<bool FP32A>
__device__ __forceinline__ void gemm_body(const void* __restrict__ Ap,
                                          const float* __restrict__ W,
                                          const unsigned short* __restrict__ Wsp,
                                          unsigned short* __restrict__ C,
                                          int nrows, int rb) {
    __shared__ unsigned short smem[2 * WHALF];  // WtH | WtL ; reused as Cs[128][68]
    unsigned short* WtH = smem;
    unsigned short* WtL = smem + WHALF;
    int t = threadIdx.x;
    int row0 = rb * 128;
    int wv = t >> 6, lane = t & 63, m = lane & 15, q = lane >> 4;
    long rowA = row0 + wv * 32 + m;
    long rowB = rowA + 16;

    short8 a[2][4];
#pragma unroll
    for (int kc = 0; kc < 4; ++kc) {
        int ko = kc * 32 + q * 8;
        if (FP32A) {
            const float* Af = (const float*)Ap;
            float4 f0 = {0,0,0,0}, f1 = {0,0,0,0}, g0 = {0,0,0,0}, g1 = {0,0,0,0};
            if (rowA < nrows) {
                f0 = *(const float4*)(Af + rowA * 128 + ko);
                f1 = *(const float4*)(Af + rowA * 128 + ko + 4);
            }
            if (rowB < nrows) {
                g0 = *(const float4*)(Af + rowB * 128 + ko);
                g1 = *(const float4*)(Af + rowB * 128 + ko + 4);
            }
            union { short8 s; unsigned short u[8]; } ua, ub;
            ua.u[0] = f2bf(f0.x); ua.u[1] = f2bf(f0.y); ua.u[2] = f2bf(f0.z); ua.u[3] = f2bf(f0.w);
            ua.u[4] = f2bf(f1.x); ua.u[5] = f2bf(f1.y); ua.u[6] = f2bf(f1.z); ua.u[7] = f2bf(f1.w);
            ub.u[0] = f2bf(g0.x); ub.u[1] = f2bf(g0.y); ub.u[2] = f2bf(g0.z); ub.u[3] = f2bf(g0.w);
            ub.u[4] = f2bf(g1.x); ub.u[5] = f2bf(g1.y); ub.u[6] = f2bf(g1.z); ub.u[7] = f2bf(g1.w);
            a[0][kc] = ua.s; a[1][kc] = ub.s;
        } else {
            const unsigned short* Ab = (const unsigned short*)Ap;
            short8 z = {};
            a[0][kc] = (rowA < nrows) ? *(const short8*)(Ab + rowA * 128 + ko) : z;
            a[1][kc] = (rowB < nrows) ? *(const short8*)(Ab + rowB * 128 + ko) : z;
        }
    }

    for (int half = 0; half < 2; ++half) {
        int c0 = half * 64;
        __syncthreads();
        if (FP32A) {
            for (int idx = t; idx < 64 * 128; idx += 256) {
                int k = idx >> 6, c = idx & 63;
                float w = W[k * 128 + c0 + c];
                unsigned short hb = f2bf(w);
                WtH[c * 136 + k] = hb;
                WtL[c * 136 + k] = f2bf(w - bf2f(hb));
            }
        } else {
            // pre-split W: straight 34 KB memcpy (2176 uint4)
            const uint4* srcw = (const uint4*)(Wsp + (size_t)half * 2 * WHALF);
            uint4* dstw = (uint4*)smem;
            for (int i = t; i < 2176; i += 256) dstw[i] = srcw[i];
        }
        __syncthreads();
        f32x4 acc[2][4] = {};
#pragma unroll
        for (int kc = 0; kc < 4; ++kc) {
            int ko = kc * 32 + q * 8;
#pragma unroll
            for (int ct = 0; ct < 4; ++ct) {
                short8 bh = *(const short8*)(WtH + (ct * 16 + m) * 136 + ko);
                short8 bl = *(const short8*)(WtL + (ct * 16 + m) * 136 + ko);
                acc[0][ct] = __builtin_amdgcn_mfma_f32_16x16x32_bf16(a[0][kc], bh, acc[0][ct], 0, 0, 0);
                acc[0][ct] = __builtin_amdgcn_mfma_f32_16x16x32_bf16(a[0][kc], bl, acc[0][ct], 0, 0, 0);
                acc[1][ct] = __builtin_amdgcn_mfma_f32_16x16x32_bf16(a[1][kc], bh, acc[1][ct], 0, 0, 0);
                acc[1][ct] = __builtin_amdgcn_mfma_f32_16x16x32_bf16(a[1][kc], bl, acc[1][ct], 0, 0, 0);
            }
        }
        __syncthreads();
        unsigned short* Cs = smem;  // [128][68]
#pragma unroll
        for (int rt = 0; rt < 2; ++rt)
#pragma unroll
            for (int ct = 0; ct < 4; ++ct)
#pragma unroll
                for (int r = 0; r < 4; ++r) {
                    int rl = wv * 32 + rt * 16 + q * 4 + r;
                    Cs[rl * 68 + ct * 16 + m] = f2bf(acc[rt][ct][r]);
                }
        __syncthreads();
        for (int idx = t; idx < 128 * 16; idx += 256) {
            int row = idx >> 4, ch = idx & 15;
            long grow = row0 + row;
            if (grow < nrows)
                *(ushort4*)(C + grow * 128 + c0 + ch * 4) = *(const ushort4*)(Cs + row * 68 + ch * 4);
        }
    }
}

// ---------------- direct binning: edges -> 256 global sub-bins ----------------
__device__ void binall_body(const int* __restrict__ src, const int* __restrict__ dst,
                            unsigned* __restrict__ bins2, unsigned* __restrict__ tail2,
                            int b) {
    __shared__ unsigned cnt[NSB];
    __shared__ unsigned cur[NSB];
    int t = threadIdx.x;
    cnt[t] = 0;
    __syncthreads();
    const int nvec = EE / 4;                 // 400000
    int csz = (nvec + NSB - 1) / NSB;        // 1563
    int i0 = b * csz;
    int i1 = i0 + csz; if (i1 > nvec) i1 = nvec;
    const int4* d4 = (const int4*)dst;
    const int4* s4 = (const int4*)src;
    for (int i = i0 + t; i < i1; i += 256) {
        int4 d = d4[i];
        atomicAdd(&cnt[(unsigned)d.x / SUBW], 1u);
        atomicAdd(&cnt[(unsigned)d.y / SUBW], 1u);
        atomicAdd(&cnt[(unsigned)d.z / SUBW], 1u);
        atomicAdd(&cnt[(unsigned)d.w / SUBW], 1u);
    }
    __syncthreads();
    cur[t] = atomicAdd(&tail2[t], cnt[t]);   // base within sub-bin region
    __syncthreads();
    for (int i = i0 + t; i < i1; i += 256) {
        int4 d = d4[i];
        int4 s = s4[i];
        int dd[4] = {d.x, d.y, d.z, d.w};
        int ss[4] = {s.x, s.y, s.z, s.w};
#pragma unroll
        for (int c = 0; c < 4; ++c) {
            unsigned gsb = (unsigned)dd[c] / SUBW;
            unsigned p = atomicAdd(&cur[gsb], 1u);
            if (p < (unsigned)CAP2)
                bins2[(size_t)gsb * CAP2 + p] =
                    ((unsigned)(dd[c] - gsb * SUBW) << 17) | (unsigned)ss[c];
        }
    }
}

// ---------------- K1: gemm layer 0 (fp32 A) || binall, block-range split ----------------
__global__ __launch_bounds__(256) void k_gemm0_bin(const float* __restrict__ x,
                                                   const float* __restrict__ W,
                                                   unsigned short* __restrict__ C,
                                                   const int* __restrict__ src,
                                                   const int* __restrict__ dst,
                                                   unsigned* __restrict__ bins2,
                                                   unsigned* __restrict__ tail2) {
    if (blockIdx.x < GEMM_BLOCKS)
        gemm_body<true>(x, W, nullptr, C, NN, blockIdx.x);
    else
        binall_body(src, dst, bins2, tail2, blockIdx.x - GEMM_BLOCKS);
}

__global__ __launch_bounds__(256) void k_gemm(const unsigned short* __restrict__ A,
                                              const unsigned short* __restrict__ Wsp,
                                              unsigned short* __restrict__ C) {
    gemm_body<false>(A, nullptr, Wsp, C, NN, blockIdx.x);
}

// ---------------- k_build: tail-prefix + hist + scan -> rp,dinv + scatter, fused ----------------
__global__ __launch_bounds__(256) void k_build(const unsigned* __restrict__ bins2,
                                               const unsigned* __restrict__ tail2,
                                               int* __restrict__ rp,
                                               float* __restrict__ dinv,
                                               int* __restrict__ ssrc,
                                               float* __restrict__ pooled) {
    __shared__ int hist[SUBW];           // hist -> cursors
    __shared__ int sa[512], sd[512];
    __shared__ unsigned ta[256], tb[256];
    int b = blockIdx.x, t = threadIdx.x;

    if (b < 65) {
        int idx = b * 256 + t;
        if (idx < GG * HH + GG) pooled[idx] = 0.f;
    }

    unsigned v = tail2[t];
    ta[t] = v;
    __syncthreads();
    unsigned *sp = ta, *dp = tb;
    for (int off = 1; off < 256; off <<= 1) {
        dp[t] = sp[t] + ((t >= off) ? sp[t - off] : 0u);
        __syncthreads();
        unsigned* tmp = sp; sp = dp; dp = tmp;
    }
    unsigned base = sp[b] - tail2[b];    // exclusive prefix for this sub-bin
    unsigned m = tail2[b];
    if (m > (unsigned)CAP2) m = CAP2;

    int lo = b * SUBW;
    int nn = NN - lo; if (nn > SUBW) nn = SUBW;
    for (int i = t; i < nn; i += 256) hist[i] = 0;
    __syncthreads();

    const unsigned* bb = bins2 + (size_t)b * CAP2;
    unsigned nv = m >> 2;
    for (unsigned i = t; i < nv; i += 256) {
        uint4 u = ((const uint4*)bb)[i];
        atomicAdd(&hist[u.x >> 17], 1);
        atomicAdd(&hist[u.y >> 17], 1);
        atomicAdd(&hist[u.z >> 17], 1);
        atomicAdd(&hist[u.w >> 17], 1);
    }
    for (unsigned i = (m & ~3u) + t; i < m; i += 256)
        atomicAdd(&hist[bb[i] >> 17], 1);
    __syncthreads();

    sa[t]       = (t < nn)       ? hist[t]       : 0;
    sa[t + 256] = (t + 256 < nn) ? hist[t + 256] : 0;
    __syncthreads();
    int* s = sa; int* d = sd;
    for (int off = 1; off < 512; off <<= 1) {
        d[t]       = s[t]       + ((t >= off)       ? s[t - off]       : 0);
        d[t + 256] = s[t + 256] + ((t + 256 >= off) ? s[t + 256 - off] : 0);
        __syncthreads();
        int* tmp = s; s = d; d = tmp;
    }

    for (int i = t; i < nn; i += 256) {
        int cur0 = (int)base + (i ? s[i - 1] : 0);
        rp[lo + i]   = cur0;
        dinv[lo + i] = rsqrtf((float)(hist[i] + 1));  // +1 self-loop
    }
    __syncthreads();
    for (int i = t; i < nn; i += 256)
        hist[i] = (int)base + (i ? s[i - 1] : 0);
    if (b == 255 && t == 0) rp[NN] = EE;
    __syncthreads();

    for (unsigned i = t; i < nv; i += 256) {
        uint4 u = ((const uint4*)bb)[i];
        int p;
        p = atomicAdd(&hist[u.x >> 17], 1); ssrc[p] = (int)(u.x & 0x1FFFFu);
        p = atomicAdd(&hist[u.y >> 17], 1); ssrc[p] = (int)(u.y & 0x1FFFFu);
        p = atomicAdd(&hist[u.z >> 17], 1); ssrc[p] = (int)(u.z & 0x1FFFFu);
        p = atomicAdd(&hist[u.w >> 17], 1); ssrc[p] = (int)(u.w & 0x1FFFFu);
    }
    for (unsigned i = (m & ~3u) + t; i < m; i += 256) {
        unsigned u = bb[i];
        int p = atomicAdd(&hist[u >> 17], 1);
        ssrc[p] = (int)(u & 0x1FFFFu);
    }
}

// ---------------- edata + split-W prep ----------------
// edata: (src, dinv[src]) per edge -- pays the random dinv gather ONCE (R10).
// tail blocks: split W layers 1,2 to bf16 hi/lo in the exact gemm-LDS layout.
__global__ void k_edata(const int* __restrict__ ssrc, const float* __restrict__ dinv,
                        uint2* __restrict__ edata, const float* __restrict__ Ws,
                        unsigned short* __restrict__ wsp) {
    int b = blockIdx.x;
    if (b < EDATA_BLOCKS) {
        int i = b * 256 + threadIdx.x;
        if (i < EE) {
            int s = ssrc[i];
            edata[i] = make_uint2((unsigned)s, __float_as_uint(dinv[s]));
        }
    } else {
        int t = threadIdx.x;
        if (t < 128) {
            int e = (b - EDATA_BLOCKS) * 128 + t;   // 0..32767
            int l = e >> 14;                         // 0..1 (layer-1)
            int r = e & 16383;
            int k = r >> 7;
            int c = r & 127;
            int half = c >> 6, cl = c & 63;
            float w = Ws[(size_t)(l + 1) * 16384 + k * 128 + c];
            unsigned short hb = f2bf(w);
            unsigned short lb = f2bf(w - bf2f(hb));
            size_t base = (size_t)l * WLAYER + (size_t)half * 2 * WHALF;
            wsp[base + cl * 136 + k]         = hb;
            wsp[base + WHALF + cl * 136 + k] = lb;
        }
    }
}

// ---------------- aggregate + bias + BN + ReLU ----------------
// R10 structure (best known): one edge per FULL wave, readlane -> SGPR base +
// saddr loads, 2 ch/lane, unroll 8. R11 lesson: shfl in the address path
// regressed (75us) -- keep cross-lane ops OUT of the load chain. edata gives
// the 64-edge metadata in ONE coalesced 8B load (no random dinv gather).
__global__ __launch_bounds__(256) void k_agg(const unsigned short* __restrict__ hw,
                                             const int* __restrict__ rp,
                                             const uint2* __restrict__ edata,
                                             const float* __restrict__ dinv,
                                             const float* __restrict__ bsl,
                                             const float* __restrict__ gamma,
                                             const float* __restrict__ beta,
                                             const float* __restrict__ rm,
                                             const float* __restrict__ rv,
                                             unsigned short* __restrict__ out) {
    int lane = threadIdx.x & 63;
    int c2   = lane * 2;                       // 2 channels per lane
    int n = blockIdx.x * 4 + (threadIdx.x >> 6);
    if (n >= NN) return;
    int beg = rp[n], end = rp[n + 1];

    v2f acc0 = {0.f, 0.f}, acc1 = {0.f, 0.f};

    for (int chunk = beg; chunk < end; chunk += 64) {
        int l = chunk + lane;
        uint2 ed = (l < end) ? edata[l] : make_uint2((unsigned)n, 0u);  // pad: self, w=0
        int   e  = (int)ed.x;
        float dv = __uint_as_float(ed.y);
        int cnt = end - chunk;
        if (cnt > 64) cnt = 64;
        for (int jb = 0; jb < cnt; jb += 8) {
#pragma unroll
            for (int j = 0; j < 8; ++j) {
                int s    = __builtin_amdgcn_readlane(e, jb + j);
                float ds = __int_as_float(
                               __builtin_amdgcn_readlane(__float_as_int(dv), jb + j));
                unsigned u = *(const unsigned*)(hw + (size_t)s * HH + c2);
                v2f vv;
                vv.x = __int_as_float((int)(u << 16));
                vv.y = __int_as_float((int)(u & 0xffff0000u));
                v2f d2 = {ds, ds};
                if (j & 1) acc1 += d2 * vv;
                else       acc0 += d2 * vv;
            }
        }
    }
    v2f a = acc0 + acc1;

    // self-loop
    float di = dinv[n];
    {
        unsigned u = *(const unsigned*)(hw + (size_t)n * HH + c2);
        v2f vv;
        vv.x = __int_as_float((int)(u << 16));
        vv.y = __int_as_float((int)(u & 0xffff0000u));
        v2f d2 = {di, di};
        a += d2 * vv;
    }
    a.x *= di;
    a.y *= di;

    float g0 = gamma[c2],   g1 = gamma[c2 + 1];
    float r0 = rv[c2],      r1 = rv[c2 + 1];
    float s0 = g0 * rsqrtf(r0 + EPSV);
    float s1 = g1 * rsqrtf(r1 + EPSV);
    float b0 = fmaf(bsl[c2]     - rm[c2],     s0, beta[c2]);
    float b1 = fmaf(bsl[c2 + 1] - rm[c2 + 1], s1, beta[c2 + 1]);
    float y0 = fmaxf(fmaf(a.x, s0, b0), 0.f);
    float y1 = fmaxf(fmaf(a.y, s1, b1), 0.f);
    ushort2 o;
    o.x = f2bf(y0);
    o.y = f2bf(y1);
    *(ushort2*)(out + (size_t)n * HH + c2) = o;
}

// ---------------- global mean pool (batch sorted, bf16 input) ----------------
__global__ __launch_bounds__(128) void k_pool(const unsigned short* __restrict__ h,
                                              const int* __restrict__ batch,
                                              float* __restrict__ pooled,
                                              float* __restrict__ cnt) {
    int t = threadIdx.x;
    const int chunk = (NN + 1023) / 1024;
    int n0 = blockIdx.x * chunk;
    if (n0 >= NN) return;
    int n1 = n0 + chunk;
    if (n1 > NN) n1 = NN;
    int cur = batch[n0];
    float acc = 0.f;
    int k = 0;
    for (int n = n0; n < n1; ++n) {
        int b = batch[n];
        if (b != cur) {
            atomicAdd(&pooled[(size_t)cur * 128 + t], acc);
            if (t == 0) atomicAdd(&cnt[cur], (float)k);
            acc = 0.f; k = 0; cur = b;
        }
        acc += bf2f(h[(size_t)n * 128 + t]);
        ++k;
    }
    atomicAdd(&pooled[(size_t)cur * 128 + t], acc);
    if (t == 0) atomicAdd(&cnt[cur], (float)k);
}

// ---------------- LSTM (single step, h0=c0=0) + FC ----------------
__global__ __launch_bounds__(128) void k_head(const float* __restrict__ pooled,
                                              const float* __restrict__ cnt,
                                              const float* __restrict__ W_ih,
                                              const float* __restrict__ b_ih,
                                              const float* __restrict__ b_hh,
                                              const float* __restrict__ W_fc,
                                              const float* __restrict__ b_fc,
                                              float* __restrict__ out) {
    __shared__ float pm[128];
    __shared__ float gate[512];
    __shared__ float hn[128];
    int g = blockIdx.x, t = threadIdx.x;
    float cdiv = fmaxf(cnt[g], 1.0f);
    pm[t] = pooled[(size_t)g * 128 + t] / cdiv;
    __syncthreads();
    for (int j = t; j < 512; j += 128) {
        float acc = b_ih[j] + b_hh[j];
        const float* w = W_ih + (size_t)j * 128;
#pragma unroll 8
        for (int k = 0; k < 128; ++k) acc = fmaf(pm[k], w[k], acc);
        gate[j] = acc;
    }
    __syncthreads();
    {
        float gi = gate[t], gg = gate[256 + t], go = gate[384 + t];
        float cc = (1.f / (1.f + expf(-gi))) * tanhf(gg);
        hn[t] = (1.f / (1.f + expf(-go))) * tanhf(cc);
    }
    __syncthreads();
    if (t < 16) {
        float acc = b_fc[t];
        const float* w = W_fc + (size_t)t * 128;
#pragma unroll 8
        for (int k = 0; k < 128; ++k) acc = fmaf(hn[k], w[k], acc);
        out[(size_t)g * 16 + t] = acc;
    }
}

// ---------------- launch ----------------
extern "C" void kernel_launch(void* const* d_in, const int* in_sizes, int n_in,
                              void* d_out, int out_size, void* d_ws, size_t ws_size,
                              hipStream_t stream) {
    const float* x      = (const float*)d_in[0];
    const int*   ei     = (const int*)d_in[1];
    const int*   src    = ei;
    const int*   dst    = ei + EE;
    const int*   batch  = (const int*)d_in[2];
    const float* Ws     = (const float*)d_in[3];
    const float* bs     = (const float*)d_in[4];
    const float* gammas = (const float*)d_in[5];
    const float* betas  = (const float*)d_in[6];
    const float* rms    = (const float*)d_in[7];
    const float* rvs    = (const float*)d_in[8];
    const float* W_ih   = (const float*)d_in[9];
    // d_in[10] = W_hh (unused: h0 = 0)
    const float* b_ih   = (const float*)d_in[11];
    const float* b_hh   = (const float*)d_in[12];
    const float* W_fc   = (const float*)d_in[13];
    const float* b_fc   = (const float*)d_in[14];
    float* out = (float*)d_out;

    char* w = (char*)d_ws;
    unsigned*       tail2  = (unsigned*)(w + OFF_TL);
    float*          dinv   = (float*)(w + OFF_DNV);
    int*            rp     = (int*)(w + OFF_RP);
    int*            ssrc   = (int*)(w + OFF_SRC);
    unsigned*       bins2  = (unsigned*)(w + OFF_B2);
    uint2*          edata  = (uint2*)(w + OFF_ED);
    unsigned short* wsp    = (unsigned short*)(w + OFF_WS);
    unsigned short* hwb    = (unsigned short*)(w + OFF_HW);
    unsigned short* h0     = (unsigned short*)(w + OFF_H0);
    float*          pooled = (float*)(w + OFF_PL);
    float*          cntb   = pooled + (size_t)GG * HH;

    hipMemsetAsync(tail2, 0, 256 * 4, stream);

    k_gemm0_bin<<<GEMM_BLOCKS + NSB, 256, 0, stream>>>(x, Ws, hwb, src, dst, bins2, tail2);
    k_build<<<NSB, 256, 0, stream>>>(bins2, tail2, rp, dinv, ssrc, pooled);
    k_edata<<<EDATA_BLOCKS + 256, 256, 0, stream>>>(ssrc, dinv, edata, Ws, wsp);

    for (int l = 0; l < 3; ++l) {
        if (l > 0)
            k_gemm<<<GEMM_BLOCKS, 256, 0, stream>>>(h0, wsp + (size_t)(l - 1) * WLAYER, hwb);
        k_agg<<<(NN + 3) / 4, 256, 0, stream>>>(hwb, rp, edata, dinv,
                                                bs + l * 128, gammas + l * 128, betas + l * 128,
                                                rms + l * 128, rvs + l * 128, h0);
    }
    k_pool<<<1024, 128, 0, stream>>>(h0, batch, pooled, cntb);
    k_head<<<GG, 128, 0, stream>>>(pooled, cntb, W_ih, b_ih, b_hh, W_fc, b_fc, out);
}

// Round 13
// 417.154 us; speedup vs baseline: 1.1453x; 1.0448x over previous
//
#include <hip/hip_runtime.h>
#include <math.h>

// ---------------- problem constants ----------------
constexpr int   NN  = 100000;    // nodes
constexpr int   EE  = 1600000;   // edges
constexpr int   HH  = 128;       // hidden / in_channels
constexpr int   GG  = 128;       // graphs
constexpr float EPSV = 1e-5f;
constexpr int   NSB = 256;                     // global sub-bins
constexpr int   SUBW = (NN + NSB - 1) / NSB;   // 391 nodes per sub-bin
constexpr int   CAP2 = 8192;                   // per-sub-bin capacity (avg 6250, +24 sigma)
constexpr int   GEMM_BLOCKS = (NN + 127) / 128;  // 782
constexpr int   WHALF = 64 * 136;                // padded ushorts per (half,hl) slab = 8704
constexpr int   WLAYER = 2 * 2 * WHALF;          // per-layer split-W ushorts (2 halves x H/L)

typedef __attribute__((ext_vector_type(8))) short  short8;
typedef __attribute__((ext_vector_type(4))) float  f32x4;
typedef __attribute__((ext_vector_type(2))) float  v2f;

__device__ __forceinline__ unsigned short f2bf(float f) {
    union { float f; unsigned u; } v; v.f = f;
    unsigned r = v.u + 0x7FFF + ((v.u >> 16) & 1);   // round-to-nearest-even
    return (unsigned short)(r >> 16);
}
__device__ __forceinline__ float bf2f(unsigned short b) {
    union { unsigned u; float f; } v; v.u = ((unsigned)b) << 16;
    return v.f;
}

// ---------------- workspace layout ----------------
constexpr size_t A256(size_t x) { return (x + 255) & ~(size_t)255; }
constexpr size_t OFF_TL  = 0;                                       // tail2[256]
constexpr size_t OFF_DNV = A256(OFF_TL  + 256 * 4);                 // N floats dinv
constexpr size_t OFF_RP  = A256(OFF_DNV + (size_t)NN * 4);          // (N+1) ints
constexpr size_t OFF_SRC = A256(OFF_RP  + (size_t)(NN + 1) * 4);    // E ints sorted src
constexpr size_t OFF_B2  = A256(OFF_SRC + (size_t)EE * 4);          // 256*CAP2 uints sub-bins
constexpr size_t OFF_ED  = A256(OFF_B2  + (size_t)NSB * CAP2 * 4);  // E uint2 (src, dinv[src])
constexpr size_t OFF_WS  = A256(OFF_ED  + (size_t)EE * 8);          // 2*WLAYER ushorts split-W (layers 1,2)
constexpr size_t OFF_HW  = A256(OFF_WS  + (size_t)2 * WLAYER * 2);  // N*H bf16 (h@W)
constexpr size_t OFF_H0  = A256(OFF_HW  + (size_t)NN * HH * 2);     // N*H bf16 (h)
constexpr size_t OFF_PL  = A256(OFF_H0  + (size_t)NN * HH * 2);     // G*H f32 pooled + G f32 cnt

// ---------------- GEMM body: C[N,128] = A[N,128] @ W[128,128], MFMA bf16, split-W ----------------
template<bool FP32A>
__device__ __forceinline__ void gemm_body(const void* __restrict__ Ap,
                                          const float* __restrict__ W,
                                          const unsigned short* __restrict__ Wsp,
                                          unsigned short* __restrict__ C,
                                          int nrows, int rb) {
    __shared__ unsigned short smem[2 * WHALF];  // WtH | WtL ; reused as Cs[128][68]
    unsigned short* WtH = smem;
    unsigned short* WtL = smem + WHALF;
    int t = threadIdx.x;
    int row0 = rb * 128;
    int wv = t >> 6, lane = t & 63, m = lane & 15, q = lane >> 4;
    long rowA = row0 + wv * 32 + m;
    long rowB = rowA + 16;

    short8 a[2][4];
#pragma unroll
    for (int kc = 0; kc < 4; ++kc) {
        int ko = kc * 32 + q * 8;
        if (FP32A) {
            const float* Af = (const float*)Ap;
            float4 f0 = {0,0,0,0}, f1 = {0,0,0,0}, g0 = {0,0,0,0}, g1 = {0,0,0,0};
            if (rowA < nrows) {
                f0 = *(const float4*)(Af + rowA * 128 + ko);
                f1 = *(const float4*)(Af + rowA * 128 + ko + 4);
            }
            if (rowB < nrows) {
                g0 = *(const float4*)(Af + rowB * 128 + ko);
                g1 = *(const float4*)(Af + rowB * 128 + ko + 4);
            }
            union { short8 s; unsigned short u[8]; } ua, ub;
            ua.u[0] = f2bf(f0.x); ua.u[1] = f2bf(f0.y); ua.u[2] = f2bf(f0.z); ua.u[3] = f2bf(f0.w);
            ua.u[4] = f2bf(f1.x); ua.u[5] = f2bf(f1.y); ua.u[6] = f2bf(f1.z); ua.u[7] = f2bf(f1.w);
            ub.u[0] = f2bf(g0.x); ub.u[1] = f2bf(g0.y); ub.u[2] = f2bf(g0.z); ub.u[3] = f2bf(g0.w);
            ub.u[4] = f2bf(g1.x); ub.u[5] = f2bf(g1.y); ub.u[6] = f2bf(g1.z); ub.u[7] = f2bf(g1.w);
            a[0][kc] = ua.s; a[1][kc] = ub.s;
        } else {
            const unsigned short* Ab = (const unsigned short*)Ap;
            short8 z = {};
            a[0][kc] = (rowA < nrows) ? *(const short8*)(Ab + rowA * 128 + ko) : z;
            a[1][kc] = (rowB < nrows) ? *(const short8*)(Ab + rowB * 128 + ko) : z;
        }
    }

    for (int half = 0; half < 2; ++half) {
        int c0 = half * 64;
        __syncthreads();
        if (FP32A) {
            for (int idx = t; idx < 64 * 128; idx += 256) {
                int k = idx >> 6, c = idx & 63;
                float w = W[k * 128 + c0 + c];
                unsigned short hb = f2bf(w);
                WtH[c * 136 + k] = hb;
                WtL[c * 136 + k] = f2bf(w - bf2f(hb));
            }
        } else {
            const uint4* srcw = (const uint4*)(Wsp + (size_t)half * 2 * WHALF);
            uint4* dstw = (uint4*)smem;
            for (int i = t; i < 2176; i += 256) dstw[i] = srcw[i];
        }
        __syncthreads();
        f32x4 acc[2][4] = {};
#pragma unroll
        for (int kc = 0; kc < 4; ++kc) {
            int ko = kc * 32 + q * 8;
#pragma unroll
            for (int ct = 0; ct < 4; ++ct) {
                short8 bh = *(const short8*)(WtH + (ct * 16 + m) * 136 + ko);
                short8 bl = *(const short8*)(WtL + (ct * 16 + m) * 136 + ko);
                acc[0][ct] = __builtin_amdgcn_mfma_f32_16x16x32_bf16(a[0][kc], bh, acc[0][ct], 0, 0, 0);
                acc[0][ct] = __builtin_amdgcn_mfma_f32_16x16x32_bf16(a[0][kc], bl, acc[0][ct], 0, 0, 0);
                acc[1][ct] = __builtin_amdgcn_mfma_f32_16x16x32_bf16(a[1][kc], bh, acc[1][ct], 0, 0, 0);
                acc[1][ct] = __builtin_amdgcn_mfma_f32_16x16x32_bf16(a[1][kc], bl, acc[1][ct], 0, 0, 0);
            }
        }
        __syncthreads();
        unsigned short* Cs = smem;  // [128][68]
#pragma unroll
        for (int rt = 0; rt < 2; ++rt)
#pragma unroll
            for (int ct = 0; ct < 4; ++ct)
#pragma unroll
                for (int r = 0; r < 4; ++r) {
                    int rl = wv * 32 + rt * 16 + q * 4 + r;
                    Cs[rl * 68 + ct * 16 + m] = f2bf(acc[rt][ct][r]);
                }
        __syncthreads();
        for (int idx = t; idx < 128 * 16; idx += 256) {
            int row = idx >> 4, ch = idx & 15;
            long grow = row0 + row;
            if (grow < nrows)
                *(ushort4*)(C + grow * 128 + c0 + ch * 4) = *(const ushort4*)(Cs + row * 68 + ch * 4);
        }
    }
}

// ---------------- direct binning: edges -> 256 global sub-bins ----------------
__device__ void binall_body(const int* __restrict__ src, const int* __restrict__ dst,
                            unsigned* __restrict__ bins2, unsigned* __restrict__ tail2,
                            int b) {
    __shared__ unsigned cnt[NSB];
    __shared__ unsigned cur[NSB];
    int t = threadIdx.x;
    cnt[t] = 0;
    __syncthreads();
    const int nvec = EE / 4;                 // 400000
    int csz = (nvec + NSB - 1) / NSB;        // 1563
    int i0 = b * csz;
    int i1 = i0 + csz; if (i1 > nvec) i1 = nvec;
    const int4* d4 = (const int4*)dst;
    const int4* s4 = (const int4*)src;
    for (int i = i0 + t; i < i1; i += 256) {
        int4 d = d4[i];
        atomicAdd(&cnt[(unsigned)d.x / SUBW], 1u);
        atomicAdd(&cnt[(unsigned)d.y / SUBW], 1u);
        atomicAdd(&cnt[(unsigned)d.z / SUBW], 1u);
        atomicAdd(&cnt[(unsigned)d.w / SUBW], 1u);
    }
    __syncthreads();
    cur[t] = atomicAdd(&tail2[t], cnt[t]);   // base within sub-bin region
    __syncthreads();
    for (int i = i0 + t; i < i1; i += 256) {
        int4 d = d4[i];
        int4 s = s4[i];
        int dd[4] = {d.x, d.y, d.z, d.w};
        int ss[4] = {s.x, s.y, s.z, s.w};
#pragma unroll
        for (int c = 0; c < 4; ++c) {
            unsigned gsb = (unsigned)dd[c] / SUBW;
            unsigned p = atomicAdd(&cur[gsb], 1u);
            if (p < (unsigned)CAP2)
                bins2[(size_t)gsb * CAP2 + p] =
                    ((unsigned)(dd[c] - gsb * SUBW) << 17) | (unsigned)ss[c];
        }
    }
}

// ---------------- K1: gemm layer 0 (fp32 A) || binall, block-range split ----------------
__global__ __launch_bounds__(256) void k_gemm0_bin(const float* __restrict__ x,
                                                   const float* __restrict__ W,
                                                   unsigned short* __restrict__ C,
                                                   const int* __restrict__ src,
                                                   const int* __restrict__ dst,
                                                   unsigned* __restrict__ bins2,
                                                   unsigned* __restrict__ tail2) {
    if (blockIdx.x < GEMM_BLOCKS)
        gemm_body<true>(x, W, nullptr, C, NN, blockIdx.x);
    else
        binall_body(src, dst, bins2, tail2, blockIdx.x - GEMM_BLOCKS);
}

__global__ __launch_bounds__(256) void k_gemm(const unsigned short* __restrict__ A,
                                              const unsigned short* __restrict__ Wsp,
                                              unsigned short* __restrict__ C) {
    gemm_body<false>(A, nullptr, Wsp, C, NN, blockIdx.x);
}

// ---------------- k_build: tail-prefix + hist + scan -> rp,dinv + scatter, fused ----------------
// Blocks 0..255: CSR build per sub-bin. Blocks 256..383: split W layers 1,2
// (moved from deleted k_edata; k_build is 1 block/CU -- spare capacity).
__global__ __launch_bounds__(256) void k_build(const unsigned* __restrict__ bins2,
                                               const unsigned* __restrict__ tail2,
                                               int* __restrict__ rp,
                                               float* __restrict__ dinv,
                                               int* __restrict__ ssrc,
                                               float* __restrict__ pooled,
                                               const float* __restrict__ Ws,
                                               unsigned short* __restrict__ wsp) {
    int b = blockIdx.x, t = threadIdx.x;

    if (b >= NSB) {
        // W split: 2 layers x 16384 elems over 128 blocks x 256 threads
        int e = (b - NSB) * 256 + t;             // 0..32767
        int l = e >> 14;                          // 0..1 (layer-1)
        int r = e & 16383;
        int k = r >> 7;
        int c = r & 127;
        int half = c >> 6, cl = c & 63;
        float w = Ws[(size_t)(l + 1) * 16384 + k * 128 + c];
        unsigned short hb = f2bf(w);
        unsigned short lb = f2bf(w - bf2f(hb));
        size_t base = (size_t)l * WLAYER + (size_t)half * 2 * WHALF;
        wsp[base + cl * 136 + k]         = hb;
        wsp[base + WHALF + cl * 136 + k] = lb;
        return;
    }

    __shared__ int hist[SUBW];           // hist -> cursors
    __shared__ int sa[512], sd[512];
    __shared__ unsigned ta[256], tb[256];

    if (b < 65) {
        int idx = b * 256 + t;
        if (idx < GG * HH + GG) pooled[idx] = 0.f;
    }

    unsigned v = tail2[t];
    ta[t] = v;
    __syncthreads();
    unsigned *sp = ta, *dp = tb;
    for (int off = 1; off < 256; off <<= 1) {
        dp[t] = sp[t] + ((t >= off) ? sp[t - off] : 0u);
        __syncthreads();
        unsigned* tmp = sp; sp = dp; dp = tmp;
    }
    unsigned base = sp[b] - tail2[b];    // exclusive prefix for this sub-bin
    unsigned m = tail2[b];
    if (m > (unsigned)CAP2) m = CAP2;

    int lo = b * SUBW;
    int nn = NN - lo; if (nn > SUBW) nn = SUBW;
    for (int i = t; i < nn; i += 256) hist[i] = 0;
    __syncthreads();

    const unsigned* bb = bins2 + (size_t)b * CAP2;
    unsigned nv = m >> 2;
    for (unsigned i = t; i < nv; i += 256) {
        uint4 u = ((const uint4*)bb)[i];
        atomicAdd(&hist[u.x >> 17], 1);
        atomicAdd(&hist[u.y >> 17], 1);
        atomicAdd(&hist[u.z >> 17], 1);
        atomicAdd(&hist[u.w >> 17], 1);
    }
    for (unsigned i = (m & ~3u) + t; i < m; i += 256)
        atomicAdd(&hist[bb[i] >> 17], 1);
    __syncthreads();

    sa[t]       = (t < nn)       ? hist[t]       : 0;
    sa[t + 256] = (t + 256 < nn) ? hist[t + 256] : 0;
    __syncthreads();
    int* s = sa; int* d = sd;
    for (int off = 1; off < 512; off <<= 1) {
        d[t]       = s[t]       + ((t >= off)       ? s[t - off]       : 0);
        d[t + 256] = s[t + 256] + ((t + 256 >= off) ? s[t + 256 - off] : 0);
        __syncthreads();
        int* tmp = s; s = d; d = tmp;
    }

    for (int i = t; i < nn; i += 256) {
        int cur0 = (int)base + (i ? s[i - 1] : 0);
        rp[lo + i]   = cur0;
        dinv[lo + i] = rsqrtf((float)(hist[i] + 1));  // +1 self-loop
    }
    __syncthreads();
    for (int i = t; i < nn; i += 256)
        hist[i] = (int)base + (i ? s[i - 1] : 0);
    if (b == 255 && t == 0) rp[NN] = EE;
    __syncthreads();

    for (unsigned i = t; i < nv; i += 256) {
        uint4 u = ((const uint4*)bb)[i];
        int p;
        p = atomicAdd(&hist[u.x >> 17], 1); ssrc[p] = (int)(u.x & 0x1FFFFu);
        p = atomicAdd(&hist[u.y >> 17], 1); ssrc[p] = (int)(u.y & 0x1FFFFu);
        p = atomicAdd(&hist[u.z >> 17], 1); ssrc[p] = (int)(u.z & 0x1FFFFu);
        p = atomicAdd(&hist[u.w >> 17], 1); ssrc[p] = (int)(u.w & 0x1FFFFu);
    }
    for (unsigned i = (m & ~3u) + t; i < m; i += 256) {
        unsigned u = bb[i];
        int p = atomicAdd(&hist[u >> 17], 1);
        ssrc[p] = (int)(u & 0x1FFFFu);
    }
}

// ---------------- aggregate + bias + BN + ReLU ----------------
// R12 structure (best: 62us): one edge per FULL wave, readlane -> SGPR base +
// saddr loads, 2 ch/lane, unroll 8; cross-lane ops OUT of the load chain.
// WRITE_ED (layer 0): reads ssrc + inline dinv gather (R10 path) and WRITES
// edata as a byproduct -> deletes the separate k_edata kernel (work + gap).
template<bool WRITE_ED>
__global__ __launch_bounds__(256) void k_agg(const unsigned short* __restrict__ hw,
                                             const int* __restrict__ rp,
                                             const int* __restrict__ ssrc,
                                             uint2* __restrict__ edata,
                                             const float* __restrict__ dinv,
                                             const float* __restrict__ bsl,
                                             const float* __restrict__ gamma,
                                             const float* __restrict__ beta,
                                             const float* __restrict__ rm,
                                             const float* __restrict__ rv,
                                             unsigned short* __restrict__ out) {
    int lane = threadIdx.x & 63;
    int c2   = lane * 2;                       // 2 channels per lane
    int n = blockIdx.x * 4 + (threadIdx.x >> 6);
    if (n >= NN) return;
    int beg = rp[n], end = rp[n + 1];

    v2f acc0 = {0.f, 0.f}, acc1 = {0.f, 0.f};

    for (int chunk = beg; chunk < end; chunk += 64) {
        int l = chunk + lane;
        int   e;
        float dv;
        if (WRITE_ED) {
            bool valid = (l < end);
            e  = valid ? ssrc[l] : n;
            dv = valid ? dinv[e] : 0.f;
            if (valid) edata[l] = make_uint2((unsigned)e, __float_as_uint(dv));
        } else {
            uint2 ed = (l < end) ? ((const uint2*)edata)[l] : make_uint2((unsigned)n, 0u);
            e  = (int)ed.x;
            dv = __uint_as_float(ed.y);
        }
        int cnt = end - chunk;
        if (cnt > 64) cnt = 64;
        for (int jb = 0; jb < cnt; jb += 8) {
#pragma unroll
            for (int j = 0; j < 8; ++j) {
                int s    = __builtin_amdgcn_readlane(e, jb + j);
                float ds = __int_as_float(
                               __builtin_amdgcn_readlane(__float_as_int(dv), jb + j));
                unsigned u = *(const unsigned*)(hw + (size_t)s * HH + c2);
                v2f vv;
                vv.x = __int_as_float((int)(u << 16));
                vv.y = __int_as_float((int)(u & 0xffff0000u));
                v2f d2 = {ds, ds};
                if (j & 1) acc1 += d2 * vv;
                else       acc0 += d2 * vv;
            }
        }
    }
    v2f a = acc0 + acc1;

    // self-loop
    float di = dinv[n];
    {
        unsigned u = *(const unsigned*)(hw + (size_t)n * HH + c2);
        v2f vv;
        vv.x = __int_as_float((int)(u << 16));
        vv.y = __int_as_float((int)(u & 0xffff0000u));
        v2f d2 = {di, di};
        a += d2 * vv;
    }
    a.x *= di;
    a.y *= di;

    float g0 = gamma[c2],   g1 = gamma[c2 + 1];
    float r0 = rv[c2],      r1 = rv[c2 + 1];
    float s0 = g0 * rsqrtf(r0 + EPSV);
    float s1 = g1 * rsqrtf(r1 + EPSV);
    float b0 = fmaf(bsl[c2]     - rm[c2],     s0, beta[c2]);
    float b1 = fmaf(bsl[c2 + 1] - rm[c2 + 1], s1, beta[c2 + 1]);
    float y0 = fmaxf(fmaf(a.x, s0, b0), 0.f);
    float y1 = fmaxf(fmaf(a.y, s1, b1), 0.f);
    ushort2 o;
    o.x = f2bf(y0);
    o.y = f2bf(y1);
    *(ushort2*)(out + (size_t)n * HH + c2) = o;
}

// ---------------- global mean pool (batch sorted, bf16 input) ----------------
__global__ __launch_bounds__(128) void k_pool(const unsigned short* __restrict__ h,
                                              const int* __restrict__ batch,
                                              float* __restrict__ pooled,
                                              float* __restrict__ cnt) {
    int t = threadIdx.x;
    const int chunk = (NN + 2047) / 2048;  // 49
    int n0 = blockIdx.x * chunk;
    if (n0 >= NN) return;
    int n1 = n0 + chunk;
    if (n1 > NN) n1 = NN;
    int cur = batch[n0];
    float acc = 0.f;
    int k = 0;
    for (int n = n0; n < n1; ++n) {
        int b = batch[n];
        if (b != cur) {
            atomicAdd(&pooled[(size_t)cur * 128 + t], acc);
            if (t == 0) atomicAdd(&cnt[cur], (float)k);
            acc = 0.f; k = 0; cur = b;
        }
        acc += bf2f(h[(size_t)n * 128 + t]);
        ++k;
    }
    atomicAdd(&pooled[(size_t)cur * 128 + t], acc);
    if (t == 0) atomicAdd(&cnt[cur], (float)k);
}

// ---------------- LSTM (single step, h0=c0=0) + FC ----------------
__global__ __launch_bounds__(128) void k_head(const float* __restrict__ pooled,
                                              const float* __restrict__ cnt,
                                              const float* __restrict__ W_ih,
                                              const float* __restrict__ b_ih,
                                              const float* __restrict__ b_hh,
                                              const float* __restrict__ W_fc,
                                              const float* __restrict__ b_fc,
                                              float* __restrict__ out) {
    __shared__ float pm[128];
    __shared__ float gate[512];
    __shared__ float hn[128];
    int g = blockIdx.x, t = threadIdx.x;
    float cdiv = fmaxf(cnt[g], 1.0f);
    pm[t] = pooled[(size_t)g * 128 + t] / cdiv;
    __syncthreads();
    for (int j = t; j < 512; j += 128) {
        float acc = b_ih[j] + b_hh[j];
        const float* w = W_ih + (size_t)j * 128;
#pragma unroll 8
        for (int k = 0; k < 128; ++k) acc = fmaf(pm[k], w[k], acc);
        gate[j] = acc;
    }
    __syncthreads();
    {
        float gi = gate[t], gg = gate[256 + t], go = gate[384 + t];
        float cc = (1.f / (1.f + expf(-gi))) * tanhf(gg);
        hn[t] = (1.f / (1.f + expf(-go))) * tanhf(cc);
    }
    __syncthreads();
    if (t < 16) {
        float acc = b_fc[t];
        const float* w = W_fc + (size_t)t * 128;
#pragma unroll 8
        for (int k = 0; k < 128; ++k) acc = fmaf(hn[k], w[k], acc);
        out[(size_t)g * 16 + t] = acc;
    }
}

// ---------------- launch ----------------
extern "C" void kernel_launch(void* const* d_in, const int* in_sizes, int n_in,
                              void* d_out, int out_size, void* d_ws, size_t ws_size,
                              hipStream_t stream) {
    const float* x      = (const float*)d_in[0];
    const int*   ei     = (const int*)d_in[1];
    const int*   src    = ei;
    const int*   dst    = ei + EE;
    const int*   batch  = (const int*)d_in[2];
    const float* Ws     = (const float*)d_in[3];
    const float* bs     = (const float*)d_in[4];
    const float* gammas = (const float*)d_in[5];
    const float* betas  = (const float*)d_in[6];
    const float* rms    = (const float*)d_in[7];
    const float* rvs    = (const float*)d_in[8];
    const float* W_ih   = (const float*)d_in[9];
    // d_in[10] = W_hh (unused: h0 = 0)
    const float* b_ih   = (const float*)d_in[11];
    const float* b_hh   = (const float*)d_in[12];
    const float* W_fc   = (const float*)d_in[13];
    const float* b_fc   = (const float*)d_in[14];
    float* out = (float*)d_out;

    char* w = (char*)d_ws;
    unsigned*       tail2  = (unsigned*)(w + OFF_TL);
    float*          dinv   = (float*)(w + OFF_DNV);
    int*            rp     = (int*)(w + OFF_RP);
    int*            ssrc   = (int*)(w + OFF_SRC);
    unsigned*       bins2  = (unsigned*)(w + OFF_B2);
    uint2*          edata  = (uint2*)(w + OFF_ED);
    unsigned short* wsp    = (unsigned short*)(w + OFF_WS);
    unsigned short* hwb    = (unsigned short*)(w + OFF_HW);
    unsigned short* h0     = (unsigned short*)(w + OFF_H0);
    float*          pooled = (float*)(w + OFF_PL);
    float*          cntb   = pooled + (size_t)GG * HH;

    hipMemsetAsync(tail2, 0, 256 * 4, stream);

    k_gemm0_bin<<<GEMM_BLOCKS + NSB, 256, 0, stream>>>(x, Ws, hwb, src, dst, bins2, tail2);
    k_build<<<NSB + 128, 256, 0, stream>>>(bins2, tail2, rp, dinv, ssrc, pooled, Ws, wsp);

    for (int l = 0; l < 3; ++l) {
        if (l > 0)
            k_gemm<<<GEMM_BLOCKS, 256, 0, stream>>>(h0, wsp + (size_t)(l - 1) * WLAYER, hwb);
        if (l == 0)
            k_agg<true><<<(NN + 3) / 4, 256, 0, stream>>>(hwb, rp, ssrc, edata, dinv,
                                                          bs, gammas, betas, rms, rvs, h0);
        else
            k_agg<false><<<(NN + 3) / 4, 256, 0, stream>>>(hwb, rp, ssrc, edata, dinv,
                                                           bs + l * 128, gammas + l * 128,
                                                           betas + l * 128, rms + l * 128,
                                                           rvs + l * 128, h0);
    }
    k_pool<<<2048, 128, 0, stream>>>(h0, batch, pooled, cntb);
    k_head<<<GG, 128, 0, stream>>>(pooled, cntb, W_ih, b_ih, b_hh, W_fc, b_fc, out);
}